// Round 15
// baseline (292.614 us; speedup 1.0000x reference)
//
#include <hip/hip_runtime.h>
#include <math.h>

#define NROWS 200000
#define DCOLS 512
#define NC 3
#define G1 1024
#define RPS (G1 * 32)      // 32768 rows per BODY16 grid step
#define NFULL 196608       // 6 * RPS
#define TAILB 106          // tail BODY16 blocks (R13-proven)
#define CGRID 2048

typedef float f4 __attribute__((ext_vector_type(4)));

__device__ __forceinline__ float elu1(float x) {
    return x > 0.0f ? x : __expf(x) - 1.0f;
}

__global__ void zero_sums(float* sums) {
    int t = blockIdx.x * blockDim.x + threadIdx.x;
    if (t < NC * DCOLS) sums[t] = 0.0f;
}

// R5/R13-proven BODY16 (feature stream, col-sliced)
#define BODY16(base)                                                         \
    {                                                                        \
        int lb[16]; f4 v[16];                                                \
        _Pragma("unroll") for (int j = 0; j < 16; ++j)                       \
            lb[j] = labels[(base) + 2 * j];                                  \
        _Pragma("unroll") for (int j = 0; j < 16; ++j)                       \
            v[j] = *(const f4*)(pbase + (size_t)((base) + 2 * j) * DCOLS);   \
        _Pragma("unroll") for (int j = 0; j < 16; ++j) {                     \
            f4 x = v[j];                                                     \
            if (tr) { x.x = elu1(w4.x * x.x); x.y = elu1(w4.y * x.y);        \
                      x.z = elu1(w4.z * x.z); x.w = elu1(w4.w * x.w); }      \
            if (lb[j] == 0)      a0 += x;                                    \
            else if (lb[j] == 1) a1 += x;                                    \
            else                 a2 += x;                                    \
        }                                                                    \
    }

// rn2 for rows r2, r2+1 (seq stream, wave-per-row, butterfly)
#define RN2STEP(r2)                                                          \
    {                                                                        \
        const float* sA = seq + (size_t)(r2) * DCOLS;                        \
        const float* sB = sA + DCOLS;                                        \
        f4 xA0 = *(const f4*)(sA + b0);                                      \
        f4 xA1 = *(const f4*)(sA + b1);                                      \
        f4 xB0 = *(const f4*)(sB + b0);                                      \
        f4 xB1 = *(const f4*)(sB + b1);                                      \
        float rA = 0.f, rB = 0.f, r;                                         \
        r = elu1(wv0.x * xA0.x); rA = fmaf(r, r, rA);                        \
        r = elu1(wv0.y * xA0.y); rA = fmaf(r, r, rA);                        \
        r = elu1(wv0.z * xA0.z); rA = fmaf(r, r, rA);                        \
        r = elu1(wv0.w * xA0.w); rA = fmaf(r, r, rA);                        \
        r = elu1(wv1.x * xA1.x); rA = fmaf(r, r, rA);                        \
        r = elu1(wv1.y * xA1.y); rA = fmaf(r, r, rA);                        \
        r = elu1(wv1.z * xA1.z); rA = fmaf(r, r, rA);                        \
        r = elu1(wv1.w * xA1.w); rA = fmaf(r, r, rA);                        \
        r = elu1(wv0.x * xB0.x); rB = fmaf(r, r, rB);                        \
        r = elu1(wv0.y * xB0.y); rB = fmaf(r, r, rB);                        \
        r = elu1(wv0.z * xB0.z); rB = fmaf(r, r, rB);                        \
        r = elu1(wv0.w * xB0.w); rB = fmaf(r, r, rB);                        \
        r = elu1(wv1.x * xB1.x); rB = fmaf(r, r, rB);                        \
        r = elu1(wv1.y * xB1.y); rB = fmaf(r, r, rB);                        \
        r = elu1(wv1.z * xB1.z); rB = fmaf(r, r, rB);                        \
        r = elu1(wv1.w * xB1.w); rB = fmaf(r, r, rB);                        \
        _Pragma("unroll") for (int o = 32; o; o >>= 1) {                     \
            rA += __shfl_xor(rA, o); rB += __shfl_xor(rB, o);                \
        }                                                                    \
        if (lane < 2) rn2out[(r2) + lane] = lane ? rB : rA;                  \
    }

// Pass 1: dual-stream — segsum(feature) interleaved with rn2(seq) so both
// arrays' reads are in flight from every wave concurrently.
__global__ __launch_bounds__(256) void pass1_kernel(
        const float* __restrict__ feature, const float* __restrict__ seq,
        const float* __restrict__ weight, const int* __restrict__ labels,
        const int* __restrict__ train, float* __restrict__ sums,
        float* __restrict__ rn2out) {
    const int t = threadIdx.x;
    const int c4 = (t & 127) << 2;
    const int h  = t >> 7;
    const int lane = t & 63;
    const int wv = t >> 6;
    const int b0 = 4 * lane, b1 = 256 + 4 * lane;
    const int tr = train[0];
    const f4 wv0 = *(const f4*)(weight + b0);     // rn2 weights (always)
    const f4 wv1 = *(const f4*)(weight + b1);
    f4 w4 = (f4)(0.f);
    if (tr) w4 = *(const f4*)(weight + c4);       // segsum weights (train)
    const float* __restrict__ src = tr ? seq : feature;
    const float* pbase = src + c4;
    f4 a0 = (f4)(0.f), a1 = (f4)(0.f), a2 = (f4)(0.f);

    const int ws2 = (blockIdx.x * 4 + wv) * 2;    // rn2 wave-slot row base
    #pragma unroll 1
    for (int k = 0; k < 6; ++k) {
        BODY16(blockIdx.x * 32 + h + k * RPS);
        #pragma unroll
        for (int u = 0; u < 4; ++u) {
            const int r2 = ws2 + (k * 4 + u) * (G1 * 8);
            if (r2 < NROWS) RN2STEP(r2);
        }
    }
    {   // rn2 tail iteration (it = 24)
        const int r2 = ws2 + 24 * (G1 * 8);
        if (r2 < NROWS) RN2STEP(r2);
    }
    if (blockIdx.x < TAILB)                        // segsum tail (R13 form)
        BODY16(NFULL + blockIdx.x * 32 + h);

    __shared__ float red[NC][128][4];
    const int c = t & 127;
    if (h == 1) {
        *(f4*)red[0][c] = a0;
        *(f4*)red[1][c] = a1;
        *(f4*)red[2][c] = a2;
    }
    __syncthreads();
    if (h == 0) {
        a0 += *(const f4*)red[0][c];
        a1 += *(const f4*)red[1][c];
        a2 += *(const f4*)red[2][c];
        atomicAdd(&sums[0 * DCOLS + c4 + 0], a0.x);
        atomicAdd(&sums[0 * DCOLS + c4 + 1], a0.y);
        atomicAdd(&sums[0 * DCOLS + c4 + 2], a0.z);
        atomicAdd(&sums[0 * DCOLS + c4 + 3], a0.w);
        atomicAdd(&sums[1 * DCOLS + c4 + 0], a1.x);
        atomicAdd(&sums[1 * DCOLS + c4 + 1], a1.y);
        atomicAdd(&sums[1 * DCOLS + c4 + 2], a1.z);
        atomicAdd(&sums[1 * DCOLS + c4 + 3], a1.w);
        atomicAdd(&sums[2 * DCOLS + c4 + 0], a2.x);
        atomicAdd(&sums[2 * DCOLS + c4 + 1], a2.y);
        atomicAdd(&sums[2 * DCOLS + c4 + 2], a2.z);
        atomicAdd(&sums[2 * DCOLS + c4 + 3], a2.w);
    }
}

__device__ __forceinline__ void dot3(f4 s, f4 w, f4 a0, f4 a1, f4 a2,
                                     float& d0, float& d1, float& d2) {
    float r;
    r = elu1(w.x * s.x); d0 = fmaf(r, a0.x, d0); d1 = fmaf(r, a1.x, d1); d2 = fmaf(r, a2.x, d2);
    r = elu1(w.y * s.y); d0 = fmaf(r, a0.y, d0); d1 = fmaf(r, a1.y, d1); d2 = fmaf(r, a2.y, d2);
    r = elu1(w.z * s.z); d0 = fmaf(r, a0.z, d0); d1 = fmaf(r, a1.z, d1); d2 = fmaf(r, a2.z, d2);
    r = elu1(w.w * s.w); d0 = fmaf(r, a0.w, d0); d1 = fmaf(r, a1.w, d1); d2 = fmaf(r, a2.w, d2);
}

// Pass 2: dots + softmax; rn read precomputed (broadcast loads).
__global__ __launch_bounds__(256) void cosine_softmax_kernel(
        const float* __restrict__ seq, const float* __restrict__ weight,
        const float* __restrict__ sums, const float* __restrict__ rn2in,
        float* __restrict__ out) {
    const int t = threadIdx.x;
    const int lane = t & 63;
    const int wv = t >> 6;
    const int b0 = 4 * lane, b1 = 256 + 4 * lane;
    const float inv = 1.0f / (float)(NROWS / 2);

    float p0 = 0.f, p1 = 0.f, p2 = 0.f;
    #pragma unroll
    for (int j = 0; j < 2; ++j) {
        const int idx = t + j * 256;
        float s0 = sums[idx], s1 = sums[DCOLS + idx], s2 = sums[2 * DCOLS + idx];
        p0 = fmaf(s0, s0, p0); p1 = fmaf(s1, s1, p1); p2 = fmaf(s2, s2, p2);
    }
    #pragma unroll
    for (int o = 32; o; o >>= 1) {
        p0 += __shfl_xor(p0, o); p1 += __shfl_xor(p1, o); p2 += __shfl_xor(p2, o);
    }
    __shared__ float redn[NC][4];
    if (lane == 0) { redn[0][wv] = p0; redn[1][wv] = p1; redn[2][wv] = p2; }
    __syncthreads();
    const float an0 = inv * sqrtf(redn[0][0] + redn[0][1] + redn[0][2] + redn[0][3]);
    const float an1 = inv * sqrtf(redn[1][0] + redn[1][1] + redn[1][2] + redn[1][3]);
    const float an2 = inv * sqrtf(redn[2][0] + redn[2][1] + redn[2][2] + redn[2][3]);

    const f4 w0 = *(const f4*)(weight + b0);
    const f4 w1 = *(const f4*)(weight + b1);
    const f4 a00 = *(const f4*)(sums + 0 * DCOLS + b0) * inv;
    const f4 a01 = *(const f4*)(sums + 0 * DCOLS + b1) * inv;
    const f4 a10 = *(const f4*)(sums + 1 * DCOLS + b0) * inv;
    const f4 a11 = *(const f4*)(sums + 1 * DCOLS + b1) * inv;
    const f4 a20 = *(const f4*)(sums + 2 * DCOLS + b0) * inv;
    const f4 a21 = *(const f4*)(sums + 2 * DCOLS + b1) * inv;

    const int rp = blockIdx.x * 4 + wv;
    for (int r2 = rp * 2; r2 < NROWS; r2 += CGRID * 8) {
        const float* sA = seq + (size_t)r2 * DCOLS;
        const float* sB = sA + DCOLS;
        f4 xA0 = *(const f4*)(sA + b0);
        f4 xA1 = *(const f4*)(sA + b1);
        f4 xB0 = *(const f4*)(sB + b0);
        f4 xB1 = *(const f4*)(sB + b1);
        const float rnA2 = rn2in[r2];
        const float rnB2 = rn2in[r2 + 1];

        float dA0 = 0.f, dA1 = 0.f, dA2 = 0.f;
        float dB0 = 0.f, dB1 = 0.f, dB2 = 0.f;
        dot3(xA0, w0, a00, a10, a20, dA0, dA1, dA2);
        dot3(xB0, w0, a00, a10, a20, dB0, dB1, dB2);
        dot3(xA1, w1, a01, a11, a21, dA0, dA1, dA2);
        dot3(xB1, w1, a01, a11, a21, dB0, dB1, dB2);

        #pragma unroll
        for (int o = 32; o; o >>= 1) {
            dA0 += __shfl_xor(dA0, o); dB0 += __shfl_xor(dB0, o);
            dA1 += __shfl_xor(dA1, o); dB1 += __shfl_xor(dB1, o);
            dA2 += __shfl_xor(dA2, o); dB2 += __shfl_xor(dB2, o);
        }
        if (lane < 3) {
            const float rA = sqrtf(rnA2);
            const float rB = sqrtf(rnB2);
            float sA0 = __fdividef(dA0, fmaxf(rA * an0, 1e-8f));
            float sA1 = __fdividef(dA1, fmaxf(rA * an1, 1e-8f));
            float sA2 = __fdividef(dA2, fmaxf(rA * an2, 1e-8f));
            float sB0 = __fdividef(dB0, fmaxf(rB * an0, 1e-8f));
            float sB1 = __fdividef(dB1, fmaxf(rB * an1, 1e-8f));
            float sB2 = __fdividef(dB2, fmaxf(rB * an2, 1e-8f));
            float mA = fmaxf(sA0, fmaxf(sA1, sA2));
            float mB = fmaxf(sB0, fmaxf(sB1, sB2));
            float eA0 = __expf(sA0 - mA), eA1 = __expf(sA1 - mA), eA2 = __expf(sA2 - mA);
            float eB0 = __expf(sB0 - mB), eB1 = __expf(sB1 - mB), eB2 = __expf(sB2 - mB);
            float iA = __fdividef(1.0f, eA0 + eA1 + eA2);
            float iB = __fdividef(1.0f, eB0 + eB1 + eB2);
            float pA = (lane == 0) ? eA0 : (lane == 1 ? eA1 : eA2);
            float pB = (lane == 0) ? eB0 : (lane == 1 ? eB1 : eB2);
            out[(size_t)r2 * 3 + lane] = pA * iA;
            out[(size_t)(r2 + 1) * 3 + lane] = pB * iB;
        }
    }
}

extern "C" void kernel_launch(void* const* d_in, const int* in_sizes, int n_in,
                              void* d_out, int out_size, void* d_ws, size_t ws_size,
                              hipStream_t stream) {
    const float* seq     = (const float*)d_in[0];
    const float* feature = (const float*)d_in[1];
    const int*   labels  = (const int*)d_in[2];
    const float* weight  = (const float*)d_in[3];
    const int*   train   = (const int*)d_in[4];
    float* out = (float*)d_out;

    float* sums = (float*)d_ws;           // 1536 floats
    float* rn2  = sums + NC * DCOLS;      // 200000 floats (~800KB, fits ws)

    zero_sums<<<6, 256, 0, stream>>>(sums);
    pass1_kernel<<<G1, 256, 0, stream>>>(feature, seq, weight, labels, train, sums, rn2);
    cosine_softmax_kernel<<<CGRID, 256, 0, stream>>>(seq, weight, sums, rn2, out);
}

// Round 16
// 224.174 us; speedup vs baseline: 1.3053x; 1.3053x over previous
//
#include <hip/hip_runtime.h>
#include <math.h>

#define NROWS 200000
#define DCOLS 512
#define NC 3
#define SGRID 1024
#define RPS (SGRID * 32)   // rows per grid step (32/block: 16 per parity)
#define NFULL 196608       // 6 * RPS
#define TAILB 106          // (NROWS-NFULL)/32 blocks cover tail exactly
#define CGRID 2048

typedef float f4 __attribute__((ext_vector_type(4)));

__device__ __forceinline__ float elu1(float x) {
    return x > 0.0f ? x : __expf(x) - 1.0f;
}

__global__ void zero_sums(float* sums) {
    int t = blockIdx.x * blockDim.x + threadIdx.x;
    if (t < NC * DCOLS) sums[t] = 0.0f;
}

// R5-proven BODY16: 16 independent rows (same parity h) in flight per
// thread, col-sliced float4, wave-uniform label branches.
#define BODY16(base)                                                         \
    {                                                                        \
        int lb[16]; f4 v[16];                                                \
        _Pragma("unroll") for (int j = 0; j < 16; ++j)                       \
            lb[j] = labels[(base) + 2 * j];                                  \
        _Pragma("unroll") for (int j = 0; j < 16; ++j)                       \
            v[j] = *(const f4*)(pbase + (size_t)((base) + 2 * j) * DCOLS);   \
        _Pragma("unroll") for (int j = 0; j < 16; ++j) {                     \
            f4 x = v[j];                                                     \
            if (tr) { x.x = elu1(w4.x * x.x); x.y = elu1(w4.y * x.y);        \
                      x.z = elu1(w4.z * x.z); x.w = elu1(w4.w * x.w); }      \
            if (lb[j] == 0)      a0 += x;                                    \
            else if (lb[j] == 1) a1 += x;                                    \
            else                 a2 += x;                                    \
        }                                                                    \
    }

__global__ __launch_bounds__(256) void segsum_kernel(
        const float* __restrict__ feature, const float* __restrict__ seq,
        const float* __restrict__ weight, const int* __restrict__ labels,
        const int* __restrict__ train, float* __restrict__ sums) {
    const int t = threadIdx.x;
    const int c4 = (t & 127) << 2;   // column base (4 floats)
    const int h  = t >> 7;           // wave-uniform row parity
    const int tr = train[0];
    f4 w4 = (f4)(0.f);
    if (tr) w4 = *(const f4*)(weight + c4);
    const float* __restrict__ src = tr ? seq : feature;
    const float* pbase = src + c4;
    f4 a0 = (f4)(0.f), a1 = (f4)(0.f), a2 = (f4)(0.f);

    for (int base = blockIdx.x * 32 + h; base < NFULL; base += RPS)
        BODY16(base);
    if (blockIdx.x < TAILB)
        BODY16(NFULL + blockIdx.x * 32 + h);

    __shared__ float red[NC][128][4];
    const int c = t & 127;
    if (h == 1) {
        *(f4*)red[0][c] = a0;
        *(f4*)red[1][c] = a1;
        *(f4*)red[2][c] = a2;
    }
    __syncthreads();
    if (h == 0) {
        a0 += *(const f4*)red[0][c];
        a1 += *(const f4*)red[1][c];
        a2 += *(const f4*)red[2][c];
        atomicAdd(&sums[0 * DCOLS + c4 + 0], a0.x);
        atomicAdd(&sums[0 * DCOLS + c4 + 1], a0.y);
        atomicAdd(&sums[0 * DCOLS + c4 + 2], a0.z);
        atomicAdd(&sums[0 * DCOLS + c4 + 3], a0.w);
        atomicAdd(&sums[1 * DCOLS + c4 + 0], a1.x);
        atomicAdd(&sums[1 * DCOLS + c4 + 1], a1.y);
        atomicAdd(&sums[1 * DCOLS + c4 + 2], a1.z);
        atomicAdd(&sums[1 * DCOLS + c4 + 3], a1.w);
        atomicAdd(&sums[2 * DCOLS + c4 + 0], a2.x);
        atomicAdd(&sums[2 * DCOLS + c4 + 1], a2.y);
        atomicAdd(&sums[2 * DCOLS + c4 + 2], a2.z);
        atomicAdd(&sums[2 * DCOLS + c4 + 3], a2.w);
    }
}

__device__ __forceinline__ void proc4(f4 s, f4 w, f4 a0, f4 a1, f4 a2,
                                      float& rn2, float& d0, float& d1, float& d2) {
    float r;
    r = elu1(w.x * s.x); rn2 = fmaf(r, r, rn2); d0 = fmaf(r, a0.x, d0); d1 = fmaf(r, a1.x, d1); d2 = fmaf(r, a2.x, d2);
    r = elu1(w.y * s.y); rn2 = fmaf(r, r, rn2); d0 = fmaf(r, a0.y, d0); d1 = fmaf(r, a1.y, d1); d2 = fmaf(r, a2.y, d2);
    r = elu1(w.z * s.z); rn2 = fmaf(r, r, rn2); d0 = fmaf(r, a0.z, d0); d1 = fmaf(r, a1.z, d1); d2 = fmaf(r, a2.z, d2);
    r = elu1(w.w * s.w); rn2 = fmaf(r, r, rn2); d0 = fmaf(r, a0.w, d0); d1 = fmaf(r, a1.w, d1); d2 = fmaf(r, a2.w, d2);
}

// Cosine+softmax with folded ave/norm derivation (no ave_norm kernel) and
// two rows per wave-iteration (R13-proven form, best total 223.8us).
__global__ __launch_bounds__(256) void cosine_softmax_kernel(
        const float* __restrict__ seq, const float* __restrict__ weight,
        const float* __restrict__ sums, float* __restrict__ out) {
    const int t = threadIdx.x;
    const int lane = t & 63;
    const int wv = t >> 6;
    const int b0 = 4 * lane, b1 = 256 + 4 * lane;
    const float inv = 1.0f / (float)(NROWS / 2);

    // ---- derive norms of the 3 class means (block-local, from sums) ----
    float p0 = 0.f, p1 = 0.f, p2 = 0.f;
    #pragma unroll
    for (int j = 0; j < 2; ++j) {
        const int idx = t + j * 256;
        float s0 = sums[idx], s1 = sums[DCOLS + idx], s2 = sums[2 * DCOLS + idx];
        p0 = fmaf(s0, s0, p0); p1 = fmaf(s1, s1, p1); p2 = fmaf(s2, s2, p2);
    }
    #pragma unroll
    for (int o = 32; o; o >>= 1) {
        p0 += __shfl_xor(p0, o); p1 += __shfl_xor(p1, o); p2 += __shfl_xor(p2, o);
    }
    __shared__ float redn[NC][4];
    if (lane == 0) { redn[0][wv] = p0; redn[1][wv] = p1; redn[2][wv] = p2; }
    __syncthreads();
    const float an0 = inv * sqrtf(redn[0][0] + redn[0][1] + redn[0][2] + redn[0][3]);
    const float an1 = inv * sqrtf(redn[1][0] + redn[1][1] + redn[1][2] + redn[1][3]);
    const float an2 = inv * sqrtf(redn[2][0] + redn[2][1] + redn[2][2] + redn[2][3]);

    // ---- per-lane ave fragments (registers) ----
    const f4 w0 = *(const f4*)(weight + b0);
    const f4 w1 = *(const f4*)(weight + b1);
    const f4 a00 = *(const f4*)(sums + 0 * DCOLS + b0) * inv;
    const f4 a01 = *(const f4*)(sums + 0 * DCOLS + b1) * inv;
    const f4 a10 = *(const f4*)(sums + 1 * DCOLS + b0) * inv;
    const f4 a11 = *(const f4*)(sums + 1 * DCOLS + b1) * inv;
    const f4 a20 = *(const f4*)(sums + 2 * DCOLS + b0) * inv;
    const f4 a21 = *(const f4*)(sums + 2 * DCOLS + b1) * inv;

    // ---- main loop: contiguous row pair per wave-iteration ----
    const int rp = blockIdx.x * 4 + wv;          // wave-slot
    for (int r2 = rp * 2; r2 < NROWS; r2 += CGRID * 8) {
        const float* sA = seq + (size_t)r2 * DCOLS;
        const float* sB = sA + DCOLS;
        f4 xA0 = *(const f4*)(sA + b0);
        f4 xA1 = *(const f4*)(sA + b1);
        f4 xB0 = *(const f4*)(sB + b0);
        f4 xB1 = *(const f4*)(sB + b1);

        float rnA = 0.f, dA0 = 0.f, dA1 = 0.f, dA2 = 0.f;
        float rnB = 0.f, dB0 = 0.f, dB1 = 0.f, dB2 = 0.f;
        proc4(xA0, w0, a00, a10, a20, rnA, dA0, dA1, dA2);
        proc4(xB0, w0, a00, a10, a20, rnB, dB0, dB1, dB2);
        proc4(xA1, w1, a01, a11, a21, rnA, dA0, dA1, dA2);
        proc4(xB1, w1, a01, a11, a21, rnB, dB0, dB1, dB2);

        #pragma unroll
        for (int o = 32; o; o >>= 1) {
            rnA += __shfl_xor(rnA, o); rnB += __shfl_xor(rnB, o);
            dA0 += __shfl_xor(dA0, o); dB0 += __shfl_xor(dB0, o);
            dA1 += __shfl_xor(dA1, o); dB1 += __shfl_xor(dB1, o);
            dA2 += __shfl_xor(dA2, o); dB2 += __shfl_xor(dB2, o);
        }
        if (lane < 3) {
            const float rA = sqrtf(rnA);
            const float rB = sqrtf(rnB);
            float sA0 = __fdividef(dA0, fmaxf(rA * an0, 1e-8f));
            float sA1 = __fdividef(dA1, fmaxf(rA * an1, 1e-8f));
            float sA2 = __fdividef(dA2, fmaxf(rA * an2, 1e-8f));
            float sB0 = __fdividef(dB0, fmaxf(rB * an0, 1e-8f));
            float sB1 = __fdividef(dB1, fmaxf(rB * an1, 1e-8f));
            float sB2 = __fdividef(dB2, fmaxf(rB * an2, 1e-8f));
            float mA = fmaxf(sA0, fmaxf(sA1, sA2));
            float mB = fmaxf(sB0, fmaxf(sB1, sB2));
            float eA0 = __expf(sA0 - mA), eA1 = __expf(sA1 - mA), eA2 = __expf(sA2 - mA);
            float eB0 = __expf(sB0 - mB), eB1 = __expf(sB1 - mB), eB2 = __expf(sB2 - mB);
            float iA = __fdividef(1.0f, eA0 + eA1 + eA2);
            float iB = __fdividef(1.0f, eB0 + eB1 + eB2);
            float pA = (lane == 0) ? eA0 : (lane == 1 ? eA1 : eA2);
            float pB = (lane == 0) ? eB0 : (lane == 1 ? eB1 : eB2);
            out[(size_t)r2 * 3 + lane] = pA * iA;
            out[(size_t)(r2 + 1) * 3 + lane] = pB * iB;
        }
    }
}

extern "C" void kernel_launch(void* const* d_in, const int* in_sizes, int n_in,
                              void* d_out, int out_size, void* d_ws, size_t ws_size,
                              hipStream_t stream) {
    const float* seq     = (const float*)d_in[0];
    const float* feature = (const float*)d_in[1];
    const int*   labels  = (const int*)d_in[2];
    const float* weight  = (const float*)d_in[3];
    const int*   train   = (const int*)d_in[4];
    float* out = (float*)d_out;

    float* sums = (float*)d_ws;           // 1536 floats

    zero_sums<<<6, 256, 0, stream>>>(sums);
    segsum_kernel<<<SGRID, 256, 0, stream>>>(feature, seq, weight, labels, train, sums);
    cosine_softmax_kernel<<<CGRID, 256, 0, stream>>>(seq, weight, sums, out);
}